// Round 11
// baseline (162.980 us; speedup 1.0000x reference)
//
#include <hip/hip_runtime.h>
#include <math.h>

#define SIG_L 128000
#define NBATCH 64
#define NROWS 257
#define HOP 128
#define NUMF 999
#define NFRM 30
#define NWIN 969
#define NB_MAX 16
#define FBINS 160          // kmap entries (>= 144 used bins)
#define TILES 9            // M = 288 rows = 144 bins x (re,im)
#define KSTEPS 16
#define FPB 64             // frames per block
#define NT 16              // ceil(999/64)
#define BETA_F 6.623413251903491f  // 1 + 10^(15/20)

typedef __attribute__((ext_vector_type(4))) short short4_t;
typedef __attribute__((ext_vector_type(8))) short short8;
typedef __attribute__((ext_vector_type(16))) float f32x16;
typedef unsigned short ushort_t;

// RNE split of fp32 into bf16 hi + bf16 lo (hi RNE; rem = v - hi exact in fp32)
__device__ inline ushort_t bf_hi_rne(float v, float* rem) {
    unsigned u = __float_as_uint(v);
    unsigned hr = (u + 0x7FFFu + ((u >> 16) & 1u)) & 0xFFFF0000u;
    *rem = v - __uint_as_float(hr);
    return (ushort_t)(hr >> 16);
}
__device__ inline ushort_t bf_rne(float v) {
    unsigned u = __float_as_uint(v);
    return (ushort_t)((u + 0x7FFFu + ((u >> 16) & 1u)) >> 16);
}

// ---------- K0: octmat scan -> hdr[32+f] = band id of bin f (or -1) ----------
__global__ void k_scan(const float* __restrict__ oct, int NB, int* __restrict__ hdr) {
    __shared__ int smin[16], smax[16];
    int tid = threadIdx.x;
    if (tid < NB) { smin[tid] = 0x7fffffff; smax[tid] = -1; }
    __syncthreads();
    for (int idx = tid; idx < NB * NROWS; idx += blockDim.x) {
        int k = idx / NROWS, f = idx % NROWS;
        if (oct[idx] != 0.0f) { atomicMin(&smin[k], f); atomicMax(&smax[k], f); }
    }
    __syncthreads();
    if (tid < FBINS) {
        int kid = -1;
        for (int k = 0; k < NB; ++k)
            if (smax[k] >= 0 && tid >= smin[k] && tid <= smax[k]) kid = k;
        hdr[32 + tid] = kid;
    }
}

// ---------- K0b: weight pack, fragment order, kk-chunked ----------
// wpack[((kk*9 + t)*2 + p)*512 + l*8 + e]  (shorts); p: 0=hi 1=lo
// A-frag: lane l holds A[row32 = l&31][k = kk*16 + (l>>5)*8 + e]
// row32 = 2m+part -> bin = t*16 + m, part: 0=re 1=im
__global__ void k_prep(const float* __restrict__ fftmat, ushort_t* __restrict__ wpack) {
    for (int u = 0; u < 2; ++u) {
        int idx = blockIdx.x * 512 + u * 256 + threadIdx.x;   // < 147456
        int e = idx & 7, l = (idx >> 3) & 63, p = (idx >> 9) & 1;
        int tt = (idx >> 10) % TILES, kk = (idx >> 10) / TILES;
        int row32 = l & 31, kq = l >> 5;
        int bin = tt * 16 + (row32 >> 1);
        int part = row32 & 1;
        int k = kk * 16 + kq * 8 + e;
        float v = fftmat[(size_t)(part ? (NROWS + bin) : bin) * 512 + 128 + k];
        float rem; ushort_t hb = bf_hi_rne(v, &rem);
        wpack[idx] = p ? bf_rne(rem) : hb;
    }
}

// ---------- K1 helpers ----------
__device__ __attribute__((always_inline)) void load_a3(
    const ushort_t* __restrict__ wpack, int kk, int tbase, int lane,
    short8* Ah, short8* Al) {
    const ushort_t* ab = wpack + (size_t)(kk * TILES + tbase) * 1024 + lane * 8;
#pragma unroll
    for (int g = 0; g < 3; ++g) {
        Ah[g] = *(const short8*)(ab + g * 1024);
        Al[g] = *(const short8*)(ab + g * 1024 + 512);
    }
}

// 9 MFMA, term-outer so each acc[g] is reused only every 3 MFMAs
__device__ __attribute__((always_inline)) void mfma_block3(
    const short8* Ah, const short8* Al, short8 Sh, short8 Sl, f32x16* acc) {
    __builtin_amdgcn_s_setprio(1);
#pragma unroll
    for (int g = 0; g < 3; ++g)
        acc[g] = __builtin_amdgcn_mfma_f32_32x32x16_bf16(Ah[g], Sh, acc[g], 0, 0, 0);
#pragma unroll
    for (int g = 0; g < 3; ++g)
        acc[g] = __builtin_amdgcn_mfma_f32_32x32x16_bf16(Ah[g], Sl, acc[g], 0, 0, 0);
#pragma unroll
    for (int g = 0; g < 3; ++g)
        acc[g] = __builtin_amdgcn_mfma_f32_32x32x16_bf16(Al[g], Sh, acc[g], 0, 0, 0);
    __builtin_amdgcn_s_setprio(0);
}

__device__ __attribute__((always_inline)) void epilogue_bands3(
    const f32x16* acc, const int* kmapS, float* bacc, int tbase, int fh, int lane) {
    const int jloc = lane & 31, kq = lane >> 5;
    const int fl = fh * 32 + jloc;
#pragma unroll
    for (int g = 0; g < 3; ++g) {
        float run = 0.0f; int runk = -1;
#pragma unroll
        for (int rr = 0; rr < 8; ++rr) {
            const int r = rr * 2;
            const int m = ((r & 2) >> 1) + 4 * (r >> 2) + 2 * kq;
            const int kid = kmapS[(tbase + g) * 16 + m];
            const float vr = acc[g][r], vi = acc[g][r + 1];
            const float e = vr * vr + vi * vi;
            if (kid != runk) {
                if (runk >= 0) atomicAdd(&bacc[runk * FPB + fl], run);
                run = 0.0f; runk = kid;
            }
            if (kid >= 0) run += e;
        }
        if (runk >= 0) atomicAdd(&bacc[runk * FPB + fl], run);
    }
}

// ---------- K1: MFMA STFT energies + band reduce ----------
// BARRIER-FREE K-loop: full B operand (all 16 kk) pre-staged in LDS as
// frag-ordered bf16 hi/lo (64 KB), one sync, then waves run independently:
// per kk = 2 ds_read_b128 + 6 coalesced A-loads from L2 (reg dbuf) + 9 MFMA.
// 384 thr = 6 waves (3 M-groups x 2 frame-halves), 3 waves/SIMD, 2 blocks/CU.
// grid (NT, NBATCH, 2). Stores band ENERGIES (sqrt in k_corr).
__global__ __launch_bounds__(384, 3) void k_stft(
    const float* __restrict__ targ, const float* __restrict__ pred,
    const ushort_t* __restrict__ wpack, const int* __restrict__ hdr,
    float* __restrict__ xbuf, float* __restrict__ ybuf, int NB) {
    __shared__ char smem[65536];
    ushort_t* Bf = (ushort_t*)smem;     // [kk][p][kq][fl 64][8] shorts
    // post-loop aliases (Bf fully consumed by then):
    float* bacc = (float*)smem;         // [NB_MAX][FPB] = 4096 B
    int* kmapS = (int*)(smem + 4096);   // 640 B

    const int tid = threadIdx.x;
    const int lane = tid & 63;
    const int wv = __builtin_amdgcn_readfirstlane(tid >> 6);  // 0..5
    const int mg = wv >> 1;             // M-group: tiles [3mg, 3mg+3)
    const int fh = wv & 1;              // frame-half (one 32-frame B tile)
    const int tbase = mg * 3;
    const int b = blockIdx.y, z = blockIdx.z;
    const int t0 = blockIdx.x * FPB;
    const float* __restrict__ sig = z ? pred : targ;
    float* __restrict__ out = z ? ybuf : xbuf;
    const size_t boff = (size_t)b * SIG_L;

    // ---- prologue: stage ALL B (16 kk) into LDS, frag-ordered, hi/lo split ----
    // i -> fl = i>>6 (frame), q = i&63 (float4 within frame's 256 samples)
    for (int i = tid; i < 4096; i += 384) {
        const int fl = i >> 6, q = i & 63;
        const int kk = q >> 2, kq = (q >> 1) & 1, e0 = (q & 1) * 4;
        float4 x = {0, 0, 0, 0};
        if (t0 + fl < NUMF)
            x = *(const float4*)(sig + boff + (size_t)(t0 + fl) * HOP + q * 4);
        float s4[4] = {x.x, x.y, x.z, x.w};
        short4_t vh, vl;
#pragma unroll
        for (int e = 0; e < 4; ++e) {
            float rem;
            vh[e] = (short)bf_hi_rne(s4[e], &rem);
            vl[e] = (short)bf_rne(rem);
        }
        const int base = ((kk * 2) * 2 + kq) * 512 + fl * 8 + e0;   // p=0
        *(short4_t*)&Bf[base] = vh;
        *(short4_t*)&Bf[base + 1024] = vl;                          // p=1 (+2*512)
    }

    f32x16 acc[3];
#pragma unroll
    for (int m = 0; m < 3; ++m)
#pragma unroll
        for (int e = 0; e < 16; ++e) acc[m][e] = 0.0f;

    short8 A0h[3], A0l[3], A1h[3], A1l[3];
    load_a3(wpack, 0, tbase, lane, A0h, A0l);
    load_a3(wpack, 1, tbase, lane, A1h, A1l);

    __syncthreads();                    // B fully staged; no more barriers in loop

    const int jloc = lane & 31, kq = lane >> 5;
    const int fl = fh * 32 + jloc;
    const int rb = kq * 512 + fl * 8;   // read base within a (kk,p) chunk

#pragma unroll 1
    for (int s = 0; s < 8; ++s) {
        const int kk = 2 * s;
        const bool doPf = (s < 7);
        short8 S0h = *(const short8*)&Bf[(kk * 4) * 512 + rb];
        short8 S0l = *(const short8*)&Bf[(kk * 4 + 2) * 512 + rb];
        short8 S1h = *(const short8*)&Bf[((kk + 1) * 4) * 512 + rb];
        short8 S1l = *(const short8*)&Bf[((kk + 1) * 4 + 2) * 512 + rb];
        mfma_block3(A0h, A0l, S0h, S0l, acc);
        if (doPf) load_a3(wpack, kk + 2, tbase, lane, A0h, A0l);
        mfma_block3(A1h, A1l, S1h, S1l, acc);
        if (doPf) load_a3(wpack, kk + 3, tbase, lane, A1h, A1l);
    }

    // ---- epilogue: energies -> band accumulate -> global ----
    __syncthreads();                    // all Bf reads done; alias as bacc/kmap
    for (int i = tid; i < NB_MAX * FPB; i += 384) bacc[i] = 0.0f;
    for (int i = tid; i < FBINS; i += 384) kmapS[i] = hdr[32 + i];
    __syncthreads();
    epilogue_bands3(acc, kmapS, bacc, tbase, fh, lane);
    __syncthreads();
    for (int idx = tid; idx < NB * FPB; idx += 384) {
        int k = idx >> 6, t = idx & (FPB - 1);
        int tg = t0 + t;
        if (tg < NUMF)
            out[((size_t)b * NB + k) * NUMF + tg] = bacc[k * FPB + t];
    }
}

// ---------- K2: sliding-window correlations (reads energies, applies sqrt) ----------
__global__ __launch_bounds__(256) void k_corr(const float* __restrict__ xbuf,
                                              const float* __restrict__ ybuf,
                                              int NB, double* __restrict__ partials) {
    const int k = blockIdx.x, b = blockIdx.y;
    const long roff = ((long)b * NB + k) * NUMF;
    __shared__ float xl[NUMF], yl[NUMF];
    __shared__ double red[256];
    const int tid = threadIdx.x;
    for (int i = tid; i < NUMF; i += 256) {
        xl[i] = sqrtf(xbuf[roff + i]);
        yl[i] = sqrtf(ybuf[roff + i]);
    }
    __syncthreads();
    double loc = 0.0;
    for (int w = tid; w < NWIN; w += 256) {
        float sx = 0, sxx = 0, syy = 0;
        for (int i = 0; i < NFRM; ++i) {
            float xv = xl[w + i], yv = yl[w + i];
            sx += xv; sxx += xv * xv; syy += yv * yv;
        }
        float alpha = sqrtf(sxx / (syy + 1e-7f));
        float sy = 0;
        for (int i = 0; i < NFRM; ++i)
            sy += fminf(alpha * yl[w + i], BETA_F * xl[w + i]);
        float mx = sx * (1.0f / NFRM), my = sy * (1.0f / NFRM);
        float cxx = 0, cyy = 0, cxy = 0;
        for (int i = 0; i < NFRM; ++i) {
            float dx = xl[w + i] - mx;
            float dy = fminf(alpha * yl[w + i], BETA_F * xl[w + i]) - my;
            cxx += dx * dx; cyy += dy * dy; cxy += dx * dy;
        }
        loc += (double)cxy / sqrt((double)cxx * (double)cyy);
    }
    red[tid] = loc;
    __syncthreads();
    for (int s = 128; s > 0; s >>= 1) {
        if (tid < s) red[tid] += red[tid + s];
        __syncthreads();
    }
    if (tid == 0) partials[b * NB + k] = red[0];
}

// ---------- K3: final deterministic reduction ----------
__global__ void k_final(const double* __restrict__ partials, int NB, float* __restrict__ out) {
    __shared__ double red[256];
    const int tid = threadIdx.x;
    const int n = NBATCH * NB;
    double s = 0.0;
    for (int i = tid; i < n; i += 256) s += partials[i];
    red[tid] = s;
    __syncthreads();
    for (int st = 128; st > 0; st >>= 1) {
        if (tid < st) red[tid] += red[tid + st];
        __syncthreads();
    }
    if (tid == 0) out[0] = (float)(-red[0] / ((double)NBATCH * NB * NWIN));
}

extern "C" void kernel_launch(void* const* d_in, const int* in_sizes, int n_in,
                              void* d_out, int out_size, void* d_ws, size_t ws_size,
                              hipStream_t stream) {
    const float* pred   = (const float*)d_in[0];
    const float* targ   = (const float*)d_in[1];
    const float* fftmat = (const float*)d_in[3];
    const float* oct    = (const float*)d_in[4];
    const int NB = in_sizes[4] / NROWS;   // 15

    char* ws = (char*)d_ws;
    int*      hdr   = (int*)ws;                          // 1 KB
    ushort_t* wpack = (ushort_t*)(ws + 1024);            // 147456 shorts = 294912 B
    size_t o1 = 1024 + (size_t)KSTEPS * TILES * 2 * 512 * 2;
    size_t xsz = (size_t)NBATCH * NB_MAX * NUMF * 4;
    float*  xbuf = (float*)(ws + o1);
    float*  ybuf = (float*)(ws + o1 + xsz);
    double* partials = (double*)(ws + o1 + 2 * xsz);

    hipLaunchKernelGGL(k_scan, dim3(1), dim3(256), 0, stream, oct, NB, hdr);
    hipLaunchKernelGGL(k_prep, dim3(288), dim3(256), 0, stream, fftmat, wpack);
    hipLaunchKernelGGL(k_stft, dim3(NT, NBATCH, 2), dim3(384), 0, stream,
                       targ, pred, wpack, hdr, xbuf, ybuf, NB);
    hipLaunchKernelGGL(k_corr, dim3(NB, NBATCH), dim3(256), 0, stream, xbuf, ybuf, NB, partials);
    hipLaunchKernelGGL(k_final, dim3(1), dim3(256), 0, stream, partials, NB, (float*)d_out);
}

// Round 12
// 116.743 us; speedup vs baseline: 1.3961x; 1.3961x over previous
//
#include <hip/hip_runtime.h>
#include <math.h>

#define SIG_L 128000
#define NBATCH 64
#define NROWS 257
#define HOP 128
#define NUMF 999
#define NFRM 30
#define NWIN 969
#define NB_MAX 16
#define FBINS 160          // kmap entries (>= 144 used bins)
#define TILES 9            // M = 288 rows = 144 bins x (re,im)
#define KSTEPS 16
#define FPB 64             // frames per block (one column)
#define NTC 16             // ceil(999/64)
#define BETA_F 6.623413251903491f  // 1 + 10^(15/20)

typedef __attribute__((ext_vector_type(4))) short short4_t;
typedef __attribute__((ext_vector_type(8))) short short8;
typedef __attribute__((ext_vector_type(16))) float f32x16;
typedef unsigned short ushort_t;

// RNE split of fp32 into bf16 hi + bf16 lo (hi RNE; rem = v - hi exact in fp32)
__device__ inline ushort_t bf_hi_rne(float v, float* rem) {
    unsigned u = __float_as_uint(v);
    unsigned hr = (u + 0x7FFFu + ((u >> 16) & 1u)) & 0xFFFF0000u;
    *rem = v - __uint_as_float(hr);
    return (ushort_t)(hr >> 16);
}
__device__ inline ushort_t bf_rne(float v) {
    unsigned u = __float_as_uint(v);
    return (ushort_t)((u + 0x7FFFu + ((u >> 16) & 1u)) >> 16);
}

// ---------- K0: octmat scan -> hdr[32+f] = band id of bin f (or -1) ----------
__global__ void k_scan(const float* __restrict__ oct, int NB, int* __restrict__ hdr) {
    __shared__ int smin[16], smax[16];
    int tid = threadIdx.x;
    if (tid < NB) { smin[tid] = 0x7fffffff; smax[tid] = -1; }
    __syncthreads();
    for (int idx = tid; idx < NB * NROWS; idx += blockDim.x) {
        int k = idx / NROWS, f = idx % NROWS;
        if (oct[idx] != 0.0f) { atomicMin(&smin[k], f); atomicMax(&smax[k], f); }
    }
    __syncthreads();
    if (tid < FBINS) {
        int kid = -1;
        for (int k = 0; k < NB; ++k)
            if (smax[k] >= 0 && tid >= smin[k] && tid <= smax[k]) kid = k;
        hdr[32 + tid] = kid;
    }
}

// ---------- K0b: weight pack, fragment order, kk-chunked ----------
// wpack[((kk*9 + t)*2 + p)*512 + l*8 + e]  (shorts); p: 0=hi 1=lo
// A-frag: lane l holds A[row32 = l&31][k = kk*16 + (l>>5)*8 + e]
// row32 = 2m+part -> bin = t*16 + m, part: 0=re 1=im
__global__ void k_prep(const float* __restrict__ fftmat, ushort_t* __restrict__ wpack) {
    for (int u = 0; u < 2; ++u) {
        int idx = blockIdx.x * 512 + u * 256 + threadIdx.x;   // < 147456
        int e = idx & 7, l = (idx >> 3) & 63, p = (idx >> 9) & 1;
        int tt = (idx >> 10) % TILES, kk = (idx >> 10) / TILES;
        int row32 = l & 31, kq = l >> 5;
        int bin = tt * 16 + (row32 >> 1);
        int part = row32 & 1;
        int k = kk * 16 + kq * 8 + e;
        float v = fftmat[(size_t)(part ? (NROWS + bin) : bin) * 512 + 128 + k];
        float rem; ushort_t hb = bf_hi_rne(v, &rem);
        wpack[idx] = p ? bf_rne(rem) : hb;
    }
}

// ---------- K1 helpers ----------
template <int MT>
__device__ __attribute__((always_inline)) void load_a(
    const ushort_t* __restrict__ wpack, int kk, int tb, int lane,
    short8* Ah, short8* Al) {
    const ushort_t* ab = wpack + (size_t)(kk * TILES + tb) * 1024 + lane * 8;
#pragma unroll
    for (int g = 0; g < MT; ++g) {
        Ah[g] = *(const short8*)(ab + g * 1024);
        Al[g] = *(const short8*)(ab + g * 1024 + 512);
    }
}

// 2-term: (Ah + Al)*S. acc[g][bt] dep distance = 2*MT.
template <int MT>
__device__ __attribute__((always_inline)) void mfma2(
    const short8* Ah, const short8* Al, const short8* S, f32x16 (*acc)[2]) {
    __builtin_amdgcn_s_setprio(1);
#pragma unroll
    for (int g = 0; g < MT; ++g)
#pragma unroll
        for (int bt = 0; bt < 2; ++bt)
            acc[g][bt] = __builtin_amdgcn_mfma_f32_32x32x16_bf16(Ah[g], S[bt], acc[g][bt], 0, 0, 0);
#pragma unroll
    for (int g = 0; g < MT; ++g)
#pragma unroll
        for (int bt = 0; bt < 2; ++bt)
            acc[g][bt] = __builtin_amdgcn_mfma_f32_32x32x16_bf16(Al[g], S[bt], acc[g][bt], 0, 0, 0);
    __builtin_amdgcn_s_setprio(0);
}

// Per-wave barrier-free K-loop + band epilogue. tb = first tile.
template <int MT>
__device__ __attribute__((always_inline)) void work(
    const ushort_t* __restrict__ wpack, const ushort_t* __restrict__ Bs,
    const int* __restrict__ kmapS, float* __restrict__ bacc, int tb, int lane) {
    const int jloc = lane & 31, kq = lane >> 5;
    f32x16 acc[MT][2];
#pragma unroll
    for (int g = 0; g < MT; ++g)
#pragma unroll
        for (int bt = 0; bt < 2; ++bt)
#pragma unroll
            for (int e = 0; e < 16; ++e) acc[g][bt][e] = 0.0f;

    short8 A0h[MT], A0l[MT], A1h[MT], A1l[MT];
    load_a<MT>(wpack, 0, tb, lane, A0h, A0l);
    load_a<MT>(wpack, 1, tb, lane, A1h, A1l);

#pragma unroll 1
    for (int s = 0; s < 8; ++s) {
        const int kk = 2 * s;
        const bool doPf = (s < 7);
        short8 S0[2], S1[2];
#pragma unroll
        for (int bt = 0; bt < 2; ++bt) {
            S0[bt] = *(const short8*)&Bs[((kk * 2 + kq) * 64 + bt * 32 + jloc) * 8];
            S1[bt] = *(const short8*)&Bs[(((kk + 1) * 2 + kq) * 64 + bt * 32 + jloc) * 8];
        }
        mfma2<MT>(A0h, A0l, S0, acc);
        if (doPf) load_a<MT>(wpack, kk + 2, tb, lane, A0h, A0l);
        mfma2<MT>(A1h, A1l, S1, acc);
        if (doPf) load_a<MT>(wpack, kk + 3, tb, lane, A1h, A1l);
    }

    // band accumulate (energies)
#pragma unroll
    for (int g = 0; g < MT; ++g) {
#pragma unroll
        for (int bt = 0; bt < 2; ++bt) {
            const int fl = bt * 32 + jloc;
            float run = 0.0f; int runk = -1;
#pragma unroll
            for (int rr = 0; rr < 8; ++rr) {
                const int m = (rr & 1) + 4 * (rr >> 1) + 2 * kq;
                const int kid = kmapS[(tb + g) * 16 + m];
                const float vr = acc[g][bt][rr * 2], vi = acc[g][bt][rr * 2 + 1];
                const float e = vr * vr + vi * vi;
                if (kid != runk) {
                    if (runk >= 0) atomicAdd(&bacc[runk * FPB + fl], run);
                    run = 0.0f; runk = kid;
                }
                if (kid >= 0) run += e;
            }
            if (runk >= 0) atomicAdd(&bacc[runk * FPB + fl], run);
        }
    }
}

// ---------- K1: MFMA STFT energies + band reduce ----------
// 2-term bf16 split: A = hi+lo (fp32-accurate), signal = plain bf16 RNE.
// Barrier-free K-loop: full single-plane B (32 KB) staged once; 4 waves =
// 4 M-groups {3,2,2,2 tiles} x one 64-frame column; A reg-dbuf from L2.
// grid (NTC, NBATCH, 2), block 256. Stores band ENERGIES (sqrt in k_corr).
__global__ __launch_bounds__(256, 2) void k_stft(
    const float* __restrict__ targ, const float* __restrict__ pred,
    const ushort_t* __restrict__ wpack, const int* __restrict__ hdr,
    float* __restrict__ xbuf, float* __restrict__ ybuf, int NB) {
    __shared__ ushort_t Bs[KSTEPS * 2 * 64 * 8];   // 32768 B, frag-ordered bf16
    __shared__ float bacc[NB_MAX * FPB];           // 4096 B
    __shared__ int kmapS[FBINS];                   // 640 B

    const int tid = threadIdx.x;
    const int lane = tid & 63;
    const int wv = __builtin_amdgcn_readfirstlane(tid >> 6);  // 0..3
    const int b = blockIdx.y, z = blockIdx.z;
    const int t0 = blockIdx.x * FPB;
    const float* __restrict__ sig = z ? pred : targ;
    float* __restrict__ out = z ? ybuf : xbuf;
    const size_t boff = (size_t)b * SIG_L;

    for (int i = tid; i < NB_MAX * FPB; i += 256) bacc[i] = 0.0f;
    for (int i = tid; i < FBINS; i += 256) kmapS[i] = hdr[32 + i];

    // ---- prologue: stage all B (single bf16 plane), coalesced loads ----
#pragma unroll
    for (int it = 0; it < 16; ++it) {
        const int i = it * 256 + tid;
        const int fl = i >> 6, q4 = i & 63;
        const int kk = q4 >> 2, kq = (q4 >> 1) & 1, e0 = (q4 & 1) * 4;
        float4 x = {0, 0, 0, 0};
        if (t0 + fl < NUMF)
            x = *(const float4*)(sig + boff + (size_t)(t0 + fl) * HOP + q4 * 4);
        short4_t vh;
        vh[0] = (short)bf_rne(x.x); vh[1] = (short)bf_rne(x.y);
        vh[2] = (short)bf_rne(x.z); vh[3] = (short)bf_rne(x.w);
        *(short4_t*)&Bs[((kk * 2 + kq) * 64 + fl) * 8 + e0] = vh;
    }
    __syncthreads();     // only barrier before epilogue: waves now independent

    if      (wv == 0) work<3>(wpack, Bs, kmapS, bacc, 0, lane);
    else if (wv == 1) work<2>(wpack, Bs, kmapS, bacc, 3, lane);
    else if (wv == 2) work<2>(wpack, Bs, kmapS, bacc, 5, lane);
    else              work<2>(wpack, Bs, kmapS, bacc, 7, lane);

    __syncthreads();
    for (int idx = tid; idx < NB * FPB; idx += 256) {
        int k = idx >> 6, t = idx & (FPB - 1);
        int tg = t0 + t;
        if (tg < NUMF)
            out[((size_t)b * NB + k) * NUMF + tg] = bacc[k * FPB + t];
    }
}

// ---------- K2: sliding-window correlations (reads energies, applies sqrt) ----------
__global__ __launch_bounds__(256) void k_corr(const float* __restrict__ xbuf,
                                              const float* __restrict__ ybuf,
                                              int NB, double* __restrict__ partials) {
    const int k = blockIdx.x, b = blockIdx.y;
    const long roff = ((long)b * NB + k) * NUMF;
    __shared__ float xl[NUMF], yl[NUMF];
    __shared__ double red[256];
    const int tid = threadIdx.x;
    for (int i = tid; i < NUMF; i += 256) {
        xl[i] = sqrtf(xbuf[roff + i]);
        yl[i] = sqrtf(ybuf[roff + i]);
    }
    __syncthreads();
    double loc = 0.0;
    for (int w = tid; w < NWIN; w += 256) {
        float sx = 0, sxx = 0, syy = 0;
        for (int i = 0; i < NFRM; ++i) {
            float xv = xl[w + i], yv = yl[w + i];
            sx += xv; sxx += xv * xv; syy += yv * yv;
        }
        float alpha = sqrtf(sxx / (syy + 1e-7f));
        float sy = 0;
        for (int i = 0; i < NFRM; ++i)
            sy += fminf(alpha * yl[w + i], BETA_F * xl[w + i]);
        float mx = sx * (1.0f / NFRM), my = sy * (1.0f / NFRM);
        float cxx = 0, cyy = 0, cxy = 0;
        for (int i = 0; i < NFRM; ++i) {
            float dx = xl[w + i] - mx;
            float dy = fminf(alpha * yl[w + i], BETA_F * xl[w + i]) - my;
            cxx += dx * dx; cyy += dy * dy; cxy += dx * dy;
        }
        loc += (double)cxy / sqrt((double)cxx * (double)cyy);
    }
    red[tid] = loc;
    __syncthreads();
    for (int s = 128; s > 0; s >>= 1) {
        if (tid < s) red[tid] += red[tid + s];
        __syncthreads();
    }
    if (tid == 0) partials[b * NB + k] = red[0];
}

// ---------- K3: final deterministic reduction ----------
__global__ void k_final(const double* __restrict__ partials, int NB, float* __restrict__ out) {
    __shared__ double red[256];
    const int tid = threadIdx.x;
    const int n = NBATCH * NB;
    double s = 0.0;
    for (int i = tid; i < n; i += 256) s += partials[i];
    red[tid] = s;
    __syncthreads();
    for (int st = 128; st > 0; st >>= 1) {
        if (tid < st) red[tid] += red[tid + st];
        __syncthreads();
    }
    if (tid == 0) out[0] = (float)(-red[0] / ((double)NBATCH * NB * NWIN));
}

extern "C" void kernel_launch(void* const* d_in, const int* in_sizes, int n_in,
                              void* d_out, int out_size, void* d_ws, size_t ws_size,
                              hipStream_t stream) {
    const float* pred   = (const float*)d_in[0];
    const float* targ   = (const float*)d_in[1];
    const float* fftmat = (const float*)d_in[3];
    const float* oct    = (const float*)d_in[4];
    const int NB = in_sizes[4] / NROWS;   // 15

    char* ws = (char*)d_ws;
    int*      hdr   = (int*)ws;                          // 1 KB
    ushort_t* wpack = (ushort_t*)(ws + 1024);            // 147456 shorts = 294912 B
    size_t o1 = 1024 + (size_t)KSTEPS * TILES * 2 * 512 * 2;
    size_t xsz = (size_t)NBATCH * NB_MAX * NUMF * 4;
    float*  xbuf = (float*)(ws + o1);
    float*  ybuf = (float*)(ws + o1 + xsz);
    double* partials = (double*)(ws + o1 + 2 * xsz);

    hipLaunchKernelGGL(k_scan, dim3(1), dim3(256), 0, stream, oct, NB, hdr);
    hipLaunchKernelGGL(k_prep, dim3(288), dim3(256), 0, stream, fftmat, wpack);
    hipLaunchKernelGGL(k_stft, dim3(NTC, NBATCH, 2), dim3(256), 0, stream,
                       targ, pred, wpack, hdr, xbuf, ybuf, NB);
    hipLaunchKernelGGL(k_corr, dim3(NB, NBATCH), dim3(256), 0, stream, xbuf, ybuf, NB, partials);
    hipLaunchKernelGGL(k_final, dim3(1), dim3(256), 0, stream, partials, NB, (float*)d_out);
}